// Round 5
// baseline (166.289 us; speedup 1.0000x reference)
//
#include <hip/hip_runtime.h>

#define NROWS 4096
#define NCOLS 4096
#define TAU 0.95f
#define MARGIN 1.0f
#define INV_TAU (1.0f / TAU)
#define LN2F 0.69314718056f

// R6: copy the fill-kernel's launch shape (the only thing on this timeline
// that saturates: 6.6 TB/s, 65536 tiny blocks). Evidence R0-R5: duration is
// invariant to cache warmth (L3-warm replays ran the same 43.5us as
// HBM-cold) => never bandwidth-bound; with grids sized for exact residency
// (16 waves/CU, zero spare) every per-wave serial stall is exposed.
// ylog: one float4 PER THREAD, 65536 waves (256/CU queued) -> per-wave
// partials in ws. norm: unchanged ballot/mbcnt row walk (proven absmax 0.0)
// in 1-wave blocks. finish folds partials + norms + rerank.

__device__ __forceinline__ int mbcnt64(unsigned long long m) {
  return __builtin_amdgcn_mbcnt_hi(
      (unsigned int)(m >> 32),
      __builtin_amdgcn_mbcnt_lo((unsigned int)m, 0));
}

// ws layout: [0, 65536) f32  ypart  (one per y-wave: sum ln y over 256 elems)
//            [65536, 69632) f32 norms (one per row)
#define YPART_N 65536

// Kernel A: 16384 blocks x 256 thr; thread reads ONE float4 of cut_y.
// Wave w of block b covers float4 indices [b*256 + w*64 + lane] -> 256
// consecutive elements per wave; ypart[b*4+w] = sum ln(y) of that chunk.
__global__ __launch_bounds__(256) void ylog_kernel(
    const float* __restrict__ cut_y, float* __restrict__ ypart) {
  const int t = threadIdx.x;
  const int lane = t & 63;
  const int wid = t >> 6;
  const float4 v = ((const float4*)cut_y)[(size_t)blockIdx.x * 256 + t];
  // y in (1e-4, 1]: product of 4 in (1e-16, 1], safe f32.
  float l2 = __log2f((v.x * v.y) * (v.z * v.w));
#pragma unroll
  for (int off = 32; off > 0; off >>= 1) l2 += __shfl_down(l2, off, 64);
  if (lane == 0) ypart[blockIdx.x * 4 + wid] = l2 * LN2F;
}

// Kernel B: one 64-thread block (one wave) per row; norms[row] = sum over
// the row of exp(f1_r/tau). Ballot/mbcnt cross-lane prefix, no LDS/barrier.
__global__ __launch_bounds__(64) void norm_kernel(
    const int* __restrict__ cut_label, float* __restrict__ norms) {
  const int lane = threadIdx.x & 63;
  const int row = blockIdx.x;
  const int4* lb = (const int4*)(cut_label + (size_t)row * NCOLS);

  // Pass 1: 16 coalesced int4 loads -> 64-bit presence mask (labels 0/1).
  unsigned int blo = 0u, bhi = 0u;
#pragma unroll
  for (int j = 0; j < 8; ++j) {
    const int4 L = lb[lane + 64 * j];
    blo |= (unsigned int)(L.x | (L.y << 1) | (L.z << 2) | (L.w << 3))
           << (4 * j);
  }
#pragma unroll
  for (int j = 0; j < 8; ++j) {
    const int4 L = lb[lane + 64 * (j + 8)];
    bhi |= (unsigned int)(L.x | (L.y << 1) | (L.z << 2) | (L.w << 3))
           << (4 * j);
  }

  // Row total T.
  int ls = __popc(blo) + __popc(bhi);
#pragma unroll
  for (int off = 32; off > 0; off >>= 1) ls += __shfl_down(ls, off, 64);
  const float Tf = (float)__shfl(ls, 0, 64);

  // Pass 2: 16 segments of 256 elements (4 per lane).
  float na = 0.f;  // sum exp(r/tau) over this lane's elements
  float Cf = 0.f;  // count consumed by earlier segments (wave-uniform)
#pragma unroll
  for (int j = 0; j < 16; ++j) {
    const unsigned int nib =
        ((j < 8) ? (blo >> (4 * j)) : (bhi >> (4 * (j - 8)))) & 0xFu;
    const unsigned long long b0 = __ballot(nib & 1u);
    const unsigned long long b1 = __ballot(nib & 2u);
    const unsigned long long b2 = __ballot(nib & 4u);
    const unsigned long long b3 = __ballot(nib & 8u);
    const int before = mbcnt64(b0) + mbcnt64(b1) + mbcnt64(b2) + mbcnt64(b3);

    float c = Cf + (float)before;            // exclusive count before my elems
    const float kb = (float)(4 * (64 * j + lane)) + Tf;  // denom = kb + (e+1)

    c += (float)(nib & 1u);
    na += __expf(((c > 0.f) ? __fdividef(2.0f * c, kb + 1.0f) : 0.f) * INV_TAU);
    c += (float)((nib >> 1) & 1u);
    na += __expf(((c > 0.f) ? __fdividef(2.0f * c, kb + 2.0f) : 0.f) * INV_TAU);
    c += (float)((nib >> 2) & 1u);
    na += __expf(((c > 0.f) ? __fdividef(2.0f * c, kb + 3.0f) : 0.f) * INV_TAU);
    c += (float)((nib >> 3) & 1u);
    na += __expf(((c > 0.f) ? __fdividef(2.0f * c, kb + 4.0f) : 0.f) * INV_TAU);

    Cf += (float)(__popcll(b0) + __popcll(b1) + __popcll(b2) + __popcll(b3));
  }

#pragma unroll
  for (int off = 32; off > 0; off >>= 1) na += __shfl_down(na, off, 64);
  if (lane == 0) norms[row] = na;
}

// Kernel C (single block): loss = -(1/NROWS) * sum_r [ysum_r / norm_r]
// + mean hinge. Thread t owns rows [t*16, t*16+16); ysum_r = sum of 16
// ypart chunks (4 float4 reads).
__global__ __launch_bounds__(256) void finish_kernel(
    const float* __restrict__ ws, const float* __restrict__ rerank_y,
    float* __restrict__ out) {
  const int t = threadIdx.x;
  const int lane = t & 63, wid = t >> 6;
  const float* ypart = ws;
  const float* norms = ws + YPART_N;

  float acc = 0.f;  // sum_r ysum_r / norm_r  (over this thread's 16 rows)
#pragma unroll
  for (int r = 0; r < 16; ++r) {
    const int row = t * 16 + r;
    const float4* yp4 = (const float4*)(ypart + row * 16);
    float s = 0.f;
#pragma unroll
    for (int i = 0; i < 4; ++i) {
      const float4 v = yp4[i];
      s += (v.x + v.y) + (v.z + v.w);
    }
    acc += __fdividef(s, norms[row]);
  }
  acc *= -(1.0f / (float)NROWS);  // attncut contribution

  float racc = 0.f;
  const float4* y4 = (const float4*)rerank_y;  // 8192 floats; float4 = 2 pairs
#pragma unroll
  for (int i = 0; i < 8; ++i) {
    float4 v = y4[t + 256 * i];
    racc += fmaxf(0.f, MARGIN - (v.x - v.y));
    racc += fmaxf(0.f, MARGIN - (v.z - v.w));
  }
  acc += racc * (1.0f / 4096.0f);

#pragma unroll
  for (int off = 32; off > 0; off >>= 1) acc += __shfl_down(acc, off, 64);
  __shared__ float wsred[4];
  if (lane == 0) wsred[wid] = acc;
  __syncthreads();
  if (t == 0) out[0] = (wsred[0] + wsred[1]) + (wsred[2] + wsred[3]);
}

extern "C" void kernel_launch(void* const* d_in, const int* in_sizes, int n_in,
                              void* d_out, int out_size, void* d_ws, size_t ws_size,
                              hipStream_t stream) {
  const float* rerank_y = (const float*)d_in[0];   // (8192, 1) f32
  const float* cut_y = (const float*)d_in[1];      // (4096, 4096, 1) f32
  // d_in[2] = rerank_label, unused by the reference loss
  const int* cut_label = (const int*)d_in[3];      // (4096, 4096) i32
  float* out = (float*)d_out;                      // scalar f32
  float* ws = (float*)d_ws;                        // 272 KB scratch used

  ylog_kernel<<<16384, 256, 0, stream>>>(cut_y, ws);
  norm_kernel<<<NROWS, 64, 0, stream>>>(cut_label, ws + YPART_N);
  finish_kernel<<<1, 256, 0, stream>>>(ws, rerank_y, out);
}

// Round 6
// 145.711 us; speedup vs baseline: 1.1412x; 1.1412x over previous
//
#include <hip/hip_runtime.h>

#define NROWS 4096
#define NCOLS 4096
#define TAU 0.95f
#define MARGIN 1.0f
#define INV_TAU (1.0f / TAU)
#define LN2F 0.69314718056f

// R7: exact R1 kernel (measured 43.5us, absmax 0.0) with ONE change: all 8
// bulk loads are __builtin_nontemporal_load (nt cache policy, L1-bypass).
// Evidence synthesis R0-R6: every variant's duration == read-bytes / ~3.0
// TB/s, independent of structure, occupancy, and warmth (L3-warm replays
// with FETCH~0.13MB still ran 43.5us); the write-only poison fill sustains
// 6.6 TB/s. Read-specific warmth-independent ceiling => latency x
// outstanding-read capacity cap (per-CU L1/TA miss tracking, ~4KB in
// flight / ~450cy ~= 3 TB/s). nt bypasses L1 allocation -> taps L2 miss
// capacity. Single-variable A/B vs R1.
typedef int v4i __attribute__((ext_vector_type(4)));
typedef float v4f __attribute__((ext_vector_type(4)));

__global__ __launch_bounds__(256) void attncut_kernel(
    const float* __restrict__ cut_y, const int* __restrict__ cut_label,
    float* __restrict__ partials) {
  const int row = blockIdx.x;
  const int t = threadIdx.x;
  const int lane = t & 63;
  const int wid = t >> 6;

  const v4i* lab4 = (const v4i*)(cut_label + (size_t)row * NCOLS);
  const v4f* yy4 = (const v4f*)(cut_y + (size_t)row * NCOLS);

  // Lane-contiguous 16B loads; nt = L1-bypass streaming policy.
  const v4i L0 = __builtin_nontemporal_load(lab4 + t);
  const v4i L1 = __builtin_nontemporal_load(lab4 + t + 256);
  const v4i L2 = __builtin_nontemporal_load(lab4 + t + 512);
  const v4i L3 = __builtin_nontemporal_load(lab4 + t + 768);
  const v4f Y0 = __builtin_nontemporal_load(yy4 + t);
  const v4f Y1 = __builtin_nontemporal_load(yy4 + t + 256);
  const v4f Y2 = __builtin_nontemporal_load(yy4 + t + 512);
  const v4f Y3 = __builtin_nontemporal_load(yy4 + t + 768);

  // Per-quarter label sums for this thread's 4-element groups (each <= 4).
  const int s0 = L0.x + L0.y + L0.z + L0.w;
  const int s1 = L1.x + L1.y + L1.z + L1.w;
  const int s2 = L2.x + L2.y + L2.z + L2.w;
  const int s3 = L3.x + L3.y + L3.z + L3.w;

  // Pack 4 sums into 16-bit fields of two u32s; one scan covers all quarters.
  unsigned int pa = (unsigned int)s0 | ((unsigned int)s1 << 16);
  unsigned int pb = (unsigned int)s2 | ((unsigned int)s3 << 16);

  unsigned int xa = pa, xb = pb;  // wave-inclusive scan
#pragma unroll
  for (int off = 1; off < 64; off <<= 1) {
    unsigned int va = __shfl_up(xa, off, 64);
    unsigned int vb = __shfl_up(xb, off, 64);
    if (lane >= off) {
      xa += va;
      xb += vb;
    }
  }
  __shared__ unsigned int wsA[4], wsB[4];
  if (lane == 63) {
    wsA[wid] = xa;
    wsB[wid] = xb;
  }
  __syncthreads();
  unsigned int prevA = 0, prevB = 0;
#pragma unroll
  for (int w = 0; w < 4; ++w)
    if (w < wid) {
      prevA += wsA[w];
      prevB += wsB[w];
    }
  const unsigned int totA = wsA[0] + wsA[1] + wsA[2] + wsA[3];
  const unsigned int totB = wsB[0] + wsB[1] + wsB[2] + wsB[3];

  const unsigned int exA = prevA + xa - pa;
  const unsigned int exB = prevB + xb - pb;

  const int q0 = (int)(totA & 0xffffu), q1 = (int)(totA >> 16);
  const int q2 = (int)(totB & 0xffffu), q3 = (int)(totB >> 16);
  const float Tf = (float)(q0 + q1 + q2 + q3);

  int c0 = (int)(exA & 0xffffu);
  int c1 = q0 + (int)(exA >> 16);
  int c2 = q0 + q1 + (int)(exB & 0xffffu);
  int c3 = q0 + q1 + q2 + (int)(exB >> 16);

  float na = 0.f;  // sum exp(r/tau)
  float l2 = 0.f;  // sum log2(y) (grouped as log2 of 4-products)

#define QSTEP(cv, LV, YV, EBASE)                                              \
  {                                                                           \
    const float db = (float)(EBASE) + Tf;                                     \
    cv += LV.x;                                                               \
    {                                                                         \
      float r = (cv > 0) ? __fdividef(2.0f * (float)cv, db + 1.0f) : 0.f;     \
      na += __expf(r * INV_TAU);                                              \
    }                                                                         \
    cv += LV.y;                                                               \
    {                                                                         \
      float r = (cv > 0) ? __fdividef(2.0f * (float)cv, db + 2.0f) : 0.f;     \
      na += __expf(r * INV_TAU);                                              \
    }                                                                         \
    cv += LV.z;                                                               \
    {                                                                         \
      float r = (cv > 0) ? __fdividef(2.0f * (float)cv, db + 3.0f) : 0.f;     \
      na += __expf(r * INV_TAU);                                              \
    }                                                                         \
    cv += LV.w;                                                               \
    {                                                                         \
      float r = (cv > 0) ? __fdividef(2.0f * (float)cv, db + 4.0f) : 0.f;     \
      na += __expf(r * INV_TAU);                                              \
    }                                                                         \
    /* y in (1e-4, 1): product of 4 in (1e-16, 1], safe f32 */                \
    l2 += __log2f(YV.x * YV.y * YV.z * YV.w);                                 \
  }

  QSTEP(c0, L0, Y0, 4 * t)
  QSTEP(c1, L1, Y1, 1024 + 4 * t)
  QSTEP(c2, L2, Y2, 2048 + 4 * t)
  QSTEP(c3, L3, Y3, 3072 + 4 * t)
#undef QSTEP

  // Block reduction of (na, l2).
#pragma unroll
  for (int off = 32; off > 0; off >>= 1) {
    na += __shfl_down(na, off, 64);
    l2 += __shfl_down(l2, off, 64);
  }
  __shared__ float nred[4], lred[4];
  if (lane == 0) {
    nred[wid] = na;
    lred[wid] = l2;
  }
  __syncthreads();
  if (t == 0) {
    const float norm = nred[0] + nred[1] + nred[2] + nred[3];
    const float lnsum = (lred[0] + lred[1] + lred[2] + lred[3]) * LN2F;
    partials[row] = -lnsum / (norm * (float)NROWS);  // distinct addr per block
  }
}

// Kernel 2 (single block): sum the 4096 per-row partials + rerank hinge loss.
__global__ __launch_bounds__(256) void finish_kernel(
    const float* __restrict__ partials, const float* __restrict__ rerank_y,
    float* __restrict__ out) {
  const int t = threadIdx.x;
  const int lane = t & 63, wid = t >> 6;

  float acc = 0.f;
  const float4* p4 = (const float4*)partials;  // 4096 floats = 1024 float4
#pragma unroll
  for (int i = 0; i < 4; ++i) {
    float4 v = p4[t + 256 * i];
    acc += (v.x + v.y) + (v.z + v.w);
  }

  float racc = 0.f;
  const float4* y4 = (const float4*)rerank_y;  // 8192 floats; float4 = 2 pairs
#pragma unroll
  for (int i = 0; i < 8; ++i) {
    float4 v = y4[t + 256 * i];
    racc += fmaxf(0.f, MARGIN - (v.x - v.y));
    racc += fmaxf(0.f, MARGIN - (v.z - v.w));
  }
  acc += racc * (1.0f / 4096.0f);

#pragma unroll
  for (int off = 32; off > 0; off >>= 1) acc += __shfl_down(acc, off, 64);
  __shared__ float ws[4];
  if (lane == 0) ws[wid] = acc;
  __syncthreads();
  if (t == 0) out[0] = (ws[0] + ws[1]) + (ws[2] + ws[3]);
}

extern "C" void kernel_launch(void* const* d_in, const int* in_sizes, int n_in,
                              void* d_out, int out_size, void* d_ws, size_t ws_size,
                              hipStream_t stream) {
  const float* rerank_y = (const float*)d_in[0];   // (8192, 1) f32
  const float* cut_y = (const float*)d_in[1];      // (4096, 4096, 1) f32
  // d_in[2] = rerank_label, unused by the reference loss
  const int* cut_label = (const int*)d_in[3];      // (4096, 4096) i32
  float* out = (float*)d_out;                      // scalar f32
  float* partials = (float*)d_ws;                  // 4096 f32 (16 KB scratch)

  attncut_kernel<<<NROWS, 256, 0, stream>>>(cut_y, cut_label, partials);
  finish_kernel<<<1, 256, 0, stream>>>(partials, rerank_y, out);
}

// Round 7
// 144.885 us; speedup vs baseline: 1.1477x; 1.0057x over previous
//
#include <hip/hip_runtime.h>

#define NROWS 4096
#define NCOLS 4096
#define TAU 0.95f
#define MARGIN 1.0f
#define INV_TAU (1.0f / TAU)
#define LN2F 0.69314718056f

// R8: R7 (nt loads, measured ~38.7us kernel / 145.7 wall) with the per-wave
// read queue DOUBLED: each block handles 2 rows, every thread issues 16 nt
// loads up-front (256B payload). Theory: read rate = bytes-in-flight /
// latency; R6 proved nt (+L1-bypass) moved the rate 3.0->3.4 TB/s, and the
// write-only fill proves the fabric does 6.6. In-flight/CU: ~128KB -> ~256KB+.
// Labels are consumed first (scan), y last -> y loads get maximal latency
// cover. Per-row arithmetic identical to R1/R7 (absmax 0.0 pedigree).
typedef int v4i __attribute__((ext_vector_type(4)));
typedef float v4f __attribute__((ext_vector_type(4)));

__global__ __launch_bounds__(256) void attncut_kernel(
    const float* __restrict__ cut_y, const int* __restrict__ cut_label,
    float* __restrict__ partials) {
  const int b = blockIdx.x;
  const int t = threadIdx.x;
  const int lane = t & 63;
  const int wid = t >> 6;
  const int r0 = b << 1;
  const int r1 = r0 | 1;

  const v4i* lA = (const v4i*)(cut_label + (size_t)r0 * NCOLS);
  const v4i* lB = (const v4i*)(cut_label + (size_t)r1 * NCOLS);
  const v4f* yA = (const v4f*)(cut_y + (size_t)r0 * NCOLS);
  const v4f* yB = (const v4f*)(cut_y + (size_t)r1 * NCOLS);

  // ---- Issue all 16 nt loads up-front (lane-contiguous 16B each). ----
  const v4i A0 = __builtin_nontemporal_load(lA + t);
  const v4i A1 = __builtin_nontemporal_load(lA + t + 256);
  const v4i A2 = __builtin_nontemporal_load(lA + t + 512);
  const v4i A3 = __builtin_nontemporal_load(lA + t + 768);
  const v4i B0 = __builtin_nontemporal_load(lB + t);
  const v4i B1 = __builtin_nontemporal_load(lB + t + 256);
  const v4i B2 = __builtin_nontemporal_load(lB + t + 512);
  const v4i B3 = __builtin_nontemporal_load(lB + t + 768);
  const v4f U0 = __builtin_nontemporal_load(yA + t);
  const v4f U1 = __builtin_nontemporal_load(yA + t + 256);
  const v4f U2 = __builtin_nontemporal_load(yA + t + 512);
  const v4f U3 = __builtin_nontemporal_load(yA + t + 768);
  const v4f V0 = __builtin_nontemporal_load(yB + t);
  const v4f V1 = __builtin_nontemporal_load(yB + t + 256);
  const v4f V2 = __builtin_nontemporal_load(yB + t + 512);
  const v4f V3 = __builtin_nontemporal_load(yB + t + 768);

  // ---- Per-quarter label sums (each <= 4), packed 16-bit, 4 scan chains. --
  const int a0 = A0.x + A0.y + A0.z + A0.w;
  const int a1 = A1.x + A1.y + A1.z + A1.w;
  const int a2 = A2.x + A2.y + A2.z + A2.w;
  const int a3 = A3.x + A3.y + A3.z + A3.w;
  const int b0 = B0.x + B0.y + B0.z + B0.w;
  const int b1 = B1.x + B1.y + B1.z + B1.w;
  const int b2 = B2.x + B2.y + B2.z + B2.w;
  const int b3 = B3.x + B3.y + B3.z + B3.w;

  unsigned int pa = (unsigned int)a0 | ((unsigned int)a1 << 16);
  unsigned int pb = (unsigned int)a2 | ((unsigned int)a3 << 16);
  unsigned int pc = (unsigned int)b0 | ((unsigned int)b1 << 16);
  unsigned int pd = (unsigned int)b2 | ((unsigned int)b3 << 16);

  unsigned int xa = pa, xb = pb, xc = pc, xd = pd;  // wave-inclusive scans
#pragma unroll
  for (int off = 1; off < 64; off <<= 1) {
    const unsigned int va = __shfl_up(xa, off, 64);
    const unsigned int vb = __shfl_up(xb, off, 64);
    const unsigned int vc = __shfl_up(xc, off, 64);
    const unsigned int vd = __shfl_up(xd, off, 64);
    if (lane >= off) {
      xa += va;
      xb += vb;
      xc += vc;
      xd += vd;
    }
  }
  __shared__ unsigned int wsA[4], wsB[4], wsC[4], wsD[4];
  if (lane == 63) {
    wsA[wid] = xa;
    wsB[wid] = xb;
    wsC[wid] = xc;
    wsD[wid] = xd;
  }
  __syncthreads();
  unsigned int prevA = 0, prevB = 0, prevC = 0, prevD = 0;
#pragma unroll
  for (int w = 0; w < 4; ++w)
    if (w < wid) {
      prevA += wsA[w];
      prevB += wsB[w];
      prevC += wsC[w];
      prevD += wsD[w];
    }
  const unsigned int totA = wsA[0] + wsA[1] + wsA[2] + wsA[3];
  const unsigned int totB = wsB[0] + wsB[1] + wsB[2] + wsB[3];
  const unsigned int totC = wsC[0] + wsC[1] + wsC[2] + wsC[3];
  const unsigned int totD = wsD[0] + wsD[1] + wsD[2] + wsD[3];

  const unsigned int exA = prevA + xa - pa;
  const unsigned int exB = prevB + xb - pb;
  const unsigned int exC = prevC + xc - pc;
  const unsigned int exD = prevD + xd - pd;

  // Row 0 bases.
  const int q0 = (int)(totA & 0xffffu), q1 = (int)(totA >> 16);
  const int q2 = (int)(totB & 0xffffu), q3 = (int)(totB >> 16);
  const float Tf0 = (float)(q0 + q1 + q2 + q3);
  int c0 = (int)(exA & 0xffffu);
  int c1 = q0 + (int)(exA >> 16);
  int c2 = q0 + q1 + (int)(exB & 0xffffu);
  int c3 = q0 + q1 + q2 + (int)(exB >> 16);
  // Row 1 bases.
  const int u0 = (int)(totC & 0xffffu), u1 = (int)(totC >> 16);
  const int u2 = (int)(totD & 0xffffu), u3 = (int)(totD >> 16);
  const float Tf1 = (float)(u0 + u1 + u2 + u3);
  int d0 = (int)(exC & 0xffffu);
  int d1 = u0 + (int)(exC >> 16);
  int d2 = u0 + u1 + (int)(exD & 0xffffu);
  int d3 = u0 + u1 + u2 + (int)(exD >> 16);

  float na0 = 0.f, l20 = 0.f, na1 = 0.f, l21 = 0.f;

#define QSTEP(cv, LV, YV, EBASE, TF, NA, LL)                                  \
  {                                                                           \
    const float db = (float)(EBASE) + TF;                                     \
    cv += LV.x;                                                               \
    {                                                                         \
      float r = (cv > 0) ? __fdividef(2.0f * (float)cv, db + 1.0f) : 0.f;     \
      NA += __expf(r * INV_TAU);                                              \
    }                                                                         \
    cv += LV.y;                                                               \
    {                                                                         \
      float r = (cv > 0) ? __fdividef(2.0f * (float)cv, db + 2.0f) : 0.f;     \
      NA += __expf(r * INV_TAU);                                              \
    }                                                                         \
    cv += LV.z;                                                               \
    {                                                                         \
      float r = (cv > 0) ? __fdividef(2.0f * (float)cv, db + 3.0f) : 0.f;     \
      NA += __expf(r * INV_TAU);                                              \
    }                                                                         \
    cv += LV.w;                                                               \
    {                                                                         \
      float r = (cv > 0) ? __fdividef(2.0f * (float)cv, db + 4.0f) : 0.f;     \
      NA += __expf(r * INV_TAU);                                              \
    }                                                                         \
    /* y in (1e-4, 1): product of 4 in (1e-16, 1], safe f32 */                \
    LL += __log2f(YV.x * YV.y * YV.z * YV.w);                                 \
  }

  QSTEP(c0, A0, U0, 4 * t, Tf0, na0, l20)
  QSTEP(c1, A1, U1, 1024 + 4 * t, Tf0, na0, l20)
  QSTEP(c2, A2, U2, 2048 + 4 * t, Tf0, na0, l20)
  QSTEP(c3, A3, U3, 3072 + 4 * t, Tf0, na0, l20)
  QSTEP(d0, B0, V0, 4 * t, Tf1, na1, l21)
  QSTEP(d1, B1, V1, 1024 + 4 * t, Tf1, na1, l21)
  QSTEP(d2, B2, V2, 2048 + 4 * t, Tf1, na1, l21)
  QSTEP(d3, B3, V3, 3072 + 4 * t, Tf1, na1, l21)
#undef QSTEP

  // Block reduction of (na0, l20, na1, l21).
#pragma unroll
  for (int off = 32; off > 0; off >>= 1) {
    na0 += __shfl_down(na0, off, 64);
    l20 += __shfl_down(l20, off, 64);
    na1 += __shfl_down(na1, off, 64);
    l21 += __shfl_down(l21, off, 64);
  }
  __shared__ float nred0[4], lred0[4], nred1[4], lred1[4];
  if (lane == 0) {
    nred0[wid] = na0;
    lred0[wid] = l20;
    nred1[wid] = na1;
    lred1[wid] = l21;
  }
  __syncthreads();
  if (t == 0) {
    const float norm0 = nred0[0] + nred0[1] + nred0[2] + nred0[3];
    const float ls0 = (lred0[0] + lred0[1] + lred0[2] + lred0[3]) * LN2F;
    partials[r0] = -ls0 / (norm0 * (float)NROWS);
  } else if (t == 64) {
    const float norm1 = nred1[0] + nred1[1] + nred1[2] + nred1[3];
    const float ls1 = (lred1[0] + lred1[1] + lred1[2] + lred1[3]) * LN2F;
    partials[r1] = -ls1 / (norm1 * (float)NROWS);
  }
}

// Kernel 2 (single block): sum the 4096 per-row partials + rerank hinge loss.
__global__ __launch_bounds__(256) void finish_kernel(
    const float* __restrict__ partials, const float* __restrict__ rerank_y,
    float* __restrict__ out) {
  const int t = threadIdx.x;
  const int lane = t & 63, wid = t >> 6;

  float acc = 0.f;
  const float4* p4 = (const float4*)partials;  // 4096 floats = 1024 float4
#pragma unroll
  for (int i = 0; i < 4; ++i) {
    float4 v = p4[t + 256 * i];
    acc += (v.x + v.y) + (v.z + v.w);
  }

  float racc = 0.f;
  const float4* y4 = (const float4*)rerank_y;  // 8192 floats; float4 = 2 pairs
#pragma unroll
  for (int i = 0; i < 8; ++i) {
    float4 v = y4[t + 256 * i];
    racc += fmaxf(0.f, MARGIN - (v.x - v.y));
    racc += fmaxf(0.f, MARGIN - (v.z - v.w));
  }
  acc += racc * (1.0f / 4096.0f);

#pragma unroll
  for (int off = 32; off > 0; off >>= 1) acc += __shfl_down(acc, off, 64);
  __shared__ float ws[4];
  if (lane == 0) ws[wid] = acc;
  __syncthreads();
  if (t == 0) out[0] = (ws[0] + ws[1]) + (ws[2] + ws[3]);
}

extern "C" void kernel_launch(void* const* d_in, const int* in_sizes, int n_in,
                              void* d_out, int out_size, void* d_ws, size_t ws_size,
                              hipStream_t stream) {
  const float* rerank_y = (const float*)d_in[0];   // (8192, 1) f32
  const float* cut_y = (const float*)d_in[1];      // (4096, 4096, 1) f32
  // d_in[2] = rerank_label, unused by the reference loss
  const int* cut_label = (const int*)d_in[3];      // (4096, 4096) i32
  float* out = (float*)d_out;                      // scalar f32
  float* partials = (float*)d_ws;                  // 4096 f32 (16 KB scratch)

  attncut_kernel<<<NROWS / 2, 256, 0, stream>>>(cut_y, cut_label, partials);
  finish_kernel<<<1, 256, 0, stream>>>(partials, rerank_y, out);
}